// Round 1
// baseline (713.068 us; speedup 1.0000x reference)
//
#include <hip/hip_runtime.h>
#include <math.h>

// Attention fwd, fp32 baseline (round 0).
// x[4,2048,256] -> qkv proj -> 8-head attention (D=32, scale 1/16) -> out proj.
// Pipeline: qkv_gemm (scatter to q/k/v [bh][n][d]) -> flash attn -> out_gemm.
// ws layout (floats): q[2M] k[2M] v[2M] z[2M] = 32 MB total.

#define DIMC 256
#define NHEADS 8
#define HDIM 32
#define SEQ 2048
#define BATCH 4
#define SCALE 0.0625f

// ---------------------------------------------------------------------------
// QKV GEMM: qkv[t][n] = x[t][:] . w_qkv[n][:] + b_qkv[n], scatter to q/k/v
// [bh][ntok][d].  M=8192, N=768, K=256. 64x64 tile, BK=16, 4x4 microtile.
// ---------------------------------------------------------------------------
__global__ __launch_bounds__(256) void qkv_gemm(const float* __restrict__ X,
                                                const float* __restrict__ W,
                                                const float* __restrict__ bias,
                                                float* __restrict__ Q,
                                                float* __restrict__ Kd,
                                                float* __restrict__ Vd) {
    const int K = DIMC;
    __shared__ float As[16][68];   // [k][m], pad to 68 (16B-aligned rows)
    __shared__ float Bs[16][68];   // [k][n]
    const int m0 = blockIdx.y * 64, n0 = blockIdx.x * 64;
    const int tid = threadIdx.x;
    const int tx = tid & 15, ty = tid >> 4;
    const int lk = tid & 15;       // k within tile
    const int lm = tid >> 4;       // row base
    float acc[4][4] = {};

    for (int kt = 0; kt < K; kt += 16) {
#pragma unroll
        for (int i = 0; i < 4; i++) {
            int m = lm + i * 16;
            As[lk][m] = X[(size_t)(m0 + m) * K + kt + lk];
            Bs[lk][m] = W[(size_t)(n0 + m) * K + kt + lk];
        }
        __syncthreads();
#pragma unroll
        for (int kk = 0; kk < 16; kk++) {
            float4 a4 = *(const float4*)&As[kk][ty * 4];
            float4 b4 = *(const float4*)&Bs[kk][tx * 4];
            const float av[4] = {a4.x, a4.y, a4.z, a4.w};
            const float bv[4] = {b4.x, b4.y, b4.z, b4.w};
#pragma unroll
            for (int i = 0; i < 4; i++)
#pragma unroll
                for (int j = 0; j < 4; j++) acc[i][j] += av[i] * bv[j];
        }
        __syncthreads();
    }

#pragma unroll
    for (int i = 0; i < 4; i++) {
        int t = m0 + ty * 4 + i;
        int bidx = t >> 11;       // t / 2048
        int ntok = t & 2047;
#pragma unroll
        for (int j = 0; j < 4; j++) {
            int n = n0 + tx * 4 + j;
            float val = acc[i][j] + bias[n];
            int which = n >> 8;   // 0=q 1=k 2=v (uniform per block since 64|256)
            int jj = n & 255;
            int h = jj >> 5, d = jj & 31;
            float* dst = (which == 0) ? Q : (which == 1) ? Kd : Vd;
            dst[((size_t)((bidx * NHEADS + h) * SEQ) + ntok) * HDIM + d] = val;
        }
    }
}

// ---------------------------------------------------------------------------
// Flash attention, fp32. grid=(32 qtiles, 32 bh), 256 thr (16x16).
// Q-tile 64x32 in LDS; loop over 32 K/V tiles of 64 rows; online softmax.
// Thread (tx,ty): S microtile rows ty*4..+4 x cols tx*4..+4; O cols tx*2..+2.
// ---------------------------------------------------------------------------
__global__ __launch_bounds__(256) void attn_kernel(const float* __restrict__ Q,
                                                   const float* __restrict__ K,
                                                   const float* __restrict__ V,
                                                   float* __restrict__ Z) {
    __shared__ float Qs[64][36];
    __shared__ float Ks[64][36];
    __shared__ float Vt[32][68];   // transposed V: [d][kk]
    __shared__ float Ps[64][68];

    const int bh = blockIdx.y;
    const int b = bh >> 3, h = bh & 7;
    const int q0 = blockIdx.x * 64;
    const float* qb = Q + (size_t)bh * SEQ * HDIM;
    const float* kb = K + (size_t)bh * SEQ * HDIM;
    const float* vb = V + (size_t)bh * SEQ * HDIM;
    const int tid = threadIdx.x;
    const int tx = tid & 15, ty = tid >> 4;

    // load Q tile (64x32 = 512 float4)
#pragma unroll
    for (int it = 0; it < 2; it++) {
        int fi = tid + it * 256;
        int r = fi >> 3, dc = (fi & 7) * 4;
        *(float4*)&Qs[r][dc] = *(const float4*)&qb[(size_t)(q0 + r) * HDIM + dc];
    }

    float m_i[4], l_i[4], o[4][2];
#pragma unroll
    for (int i = 0; i < 4; i++) {
        m_i[i] = -1e30f; l_i[i] = 0.f; o[i][0] = 0.f; o[i][1] = 0.f;
    }

    for (int k0 = 0; k0 < SEQ; k0 += 64) {
#pragma unroll
        for (int it = 0; it < 2; it++) {
            int fi = tid + it * 256;
            int r = fi >> 3, dc = (fi & 7) * 4;
            *(float4*)&Ks[r][dc] = *(const float4*)&kb[(size_t)(k0 + r) * HDIM + dc];
            float4 v4 = *(const float4*)&vb[(size_t)(k0 + r) * HDIM + dc];
            Vt[dc + 0][r] = v4.x; Vt[dc + 1][r] = v4.y;
            Vt[dc + 2][r] = v4.z; Vt[dc + 3][r] = v4.w;
        }
        __syncthreads();

        // S = Q K^T (4x4 per thread)
        float s[4][4] = {};
#pragma unroll
        for (int k4 = 0; k4 < 8; k4++) {
            float4 qv[4], kv[4];
#pragma unroll
            for (int i = 0; i < 4; i++) qv[i] = *(const float4*)&Qs[ty * 4 + i][k4 * 4];
#pragma unroll
            for (int j = 0; j < 4; j++) kv[j] = *(const float4*)&Ks[tx * 4 + j][k4 * 4];
#pragma unroll
            for (int i = 0; i < 4; i++)
#pragma unroll
                for (int j = 0; j < 4; j++)
                    s[i][j] += qv[i].x * kv[j].x + qv[i].y * kv[j].y +
                               qv[i].z * kv[j].z + qv[i].w * kv[j].w;
        }

        // online softmax per row (16-lane shuffle reduce across tx)
#pragma unroll
        for (int i = 0; i < 4; i++) {
            float tmax = -1e30f;
            float p[4];
#pragma unroll
            for (int j = 0; j < 4; j++) {
                s[i][j] *= SCALE;
                tmax = fmaxf(tmax, s[i][j]);
            }
#pragma unroll
            for (int off = 1; off < 16; off <<= 1)
                tmax = fmaxf(tmax, __shfl_xor(tmax, off, 16));
            float mnew = fmaxf(m_i[i], tmax);
            float alpha = __expf(m_i[i] - mnew);
            float lsum = 0.f;
#pragma unroll
            for (int j = 0; j < 4; j++) {
                p[j] = __expf(s[i][j] - mnew);
                lsum += p[j];
            }
#pragma unroll
            for (int off = 1; off < 16; off <<= 1)
                lsum += __shfl_xor(lsum, off, 16);
            l_i[i] = l_i[i] * alpha + lsum;
            m_i[i] = mnew;
            o[i][0] *= alpha; o[i][1] *= alpha;
            *(float4*)&Ps[ty * 4 + i][tx * 4] = make_float4(p[0], p[1], p[2], p[3]);
        }
        __syncthreads();

        // O += P V  (thread owns rows ty*4..+4, d-cols tx*2, tx*2+1)
        const int d0 = tx * 2;
#pragma unroll
        for (int kk4 = 0; kk4 < 16; kk4++) {
            float4 va = *(const float4*)&Vt[d0][kk4 * 4];
            float4 vb4 = *(const float4*)&Vt[d0 + 1][kk4 * 4];
#pragma unroll
            for (int i = 0; i < 4; i++) {
                float4 p4 = *(const float4*)&Ps[ty * 4 + i][kk4 * 4];
                o[i][0] += p4.x * va.x + p4.y * va.y + p4.z * va.z + p4.w * va.w;
                o[i][1] += p4.x * vb4.x + p4.y * vb4.y + p4.z * vb4.z + p4.w * vb4.w;
            }
        }
        __syncthreads();
    }

    // z[b][n][h*32+d] = O / l
#pragma unroll
    for (int i = 0; i < 4; i++) {
        float inv = 1.0f / l_i[i];
        int row = q0 + ty * 4 + i;
        size_t zoff = ((size_t)(b * SEQ + row)) * DIMC + h * HDIM + tx * 2;
        Z[zoff] = o[i][0] * inv;
        Z[zoff + 1] = o[i][1] * inv;
    }
}

// ---------------------------------------------------------------------------
// Out GEMM: out[t][n] = z[t][:] . w_out[n][:] + b_out[n]. M=8192,N=256,K=256.
// ---------------------------------------------------------------------------
__global__ __launch_bounds__(256) void out_gemm(const float* __restrict__ A,
                                                const float* __restrict__ W,
                                                const float* __restrict__ bias,
                                                float* __restrict__ C) {
    const int K = DIMC;
    __shared__ float As[16][68];
    __shared__ float Bs[16][68];
    const int m0 = blockIdx.y * 64, n0 = blockIdx.x * 64;
    const int tid = threadIdx.x;
    const int tx = tid & 15, ty = tid >> 4;
    const int lk = tid & 15;
    const int lm = tid >> 4;
    float acc[4][4] = {};

    for (int kt = 0; kt < K; kt += 16) {
#pragma unroll
        for (int i = 0; i < 4; i++) {
            int m = lm + i * 16;
            As[lk][m] = A[(size_t)(m0 + m) * K + kt + lk];
            Bs[lk][m] = W[(size_t)(n0 + m) * K + kt + lk];
        }
        __syncthreads();
#pragma unroll
        for (int kk = 0; kk < 16; kk++) {
            float4 a4 = *(const float4*)&As[kk][ty * 4];
            float4 b4 = *(const float4*)&Bs[kk][tx * 4];
            const float av[4] = {a4.x, a4.y, a4.z, a4.w};
            const float bv[4] = {b4.x, b4.y, b4.z, b4.w};
#pragma unroll
            for (int i = 0; i < 4; i++)
#pragma unroll
                for (int j = 0; j < 4; j++) acc[i][j] += av[i] * bv[j];
        }
        __syncthreads();
    }

#pragma unroll
    for (int i = 0; i < 4; i++) {
        int t = m0 + ty * 4 + i;
#pragma unroll
        for (int j = 0; j < 4; j++) {
            int n = n0 + tx * 4 + j;
            C[(size_t)t * DIMC + n] = acc[i][j] + bias[n];
        }
    }
}

extern "C" void kernel_launch(void* const* d_in, const int* in_sizes, int n_in,
                              void* d_out, int out_size, void* d_ws, size_t ws_size,
                              hipStream_t stream) {
    const float* x     = (const float*)d_in[0];
    const float* w_qkv = (const float*)d_in[1];
    const float* b_qkv = (const float*)d_in[2];
    const float* w_out = (const float*)d_in[3];
    const float* b_out = (const float*)d_in[4];
    float* out = (float*)d_out;

    const size_t HSZ = (size_t)BATCH * NHEADS * SEQ * HDIM;  // 2M floats
    float* q = (float*)d_ws;
    float* k = q + HSZ;
    float* v = k + HSZ;
    float* z = v + HSZ;

    qkv_gemm<<<dim3(12, 128), 256, 0, stream>>>(x, w_qkv, b_qkv, q, k, v);
    attn_kernel<<<dim3(32, 32), 256, 0, stream>>>(q, k, v, z);
    out_gemm<<<dim3(4, 128), 256, 0, stream>>>(z, w_out, b_out, out);
}

// Round 2
// 194.257 us; speedup vs baseline: 3.6707x; 3.6707x over previous
//
#include <hip/hip_runtime.h>
#include <math.h>

// Round 1: bf16-MFMA flash attention. GEMMs still fp32 (convert next round).
// qkv_gemm -> bf16 Q(pre-scaled)/K [bh][n][d], V transposed [bh][d][n]
// attn_mfma: 16x16x32 bf16 MFMA, no-max-subtraction softmax (|S|<~1.3),
//            deferred l-reduction. out_gemm: fp32, unchanged.
// ws: Q 4MB | K 4MB | V 4MB (bf16) | Z 8MB (fp32) = 20 MB.

#define DIMC 256
#define NHEADS 8
#define HDIM 32
#define SEQ 2048
#define BATCH 4
#define SCALE 0.0625f

typedef __attribute__((ext_vector_type(8))) short short8;
typedef __attribute__((ext_vector_type(4))) float f32x4;

__device__ __forceinline__ short f2bf(float f) {
    union { float f; unsigned u; } x; x.f = f;
    unsigned r = x.u + 0x7fffu + ((x.u >> 16) & 1u);
    return (short)(r >> 16);
}

// ---------------------------------------------------------------------------
// QKV GEMM: fp32 compute, bf16 scatter epilogue.
// Q[bh][n][d] *= SCALE;  K[bh][n][d];  V transposed [bh][d][n].
// ---------------------------------------------------------------------------
__global__ __launch_bounds__(256) void qkv_gemm(const float* __restrict__ X,
                                                const float* __restrict__ W,
                                                const float* __restrict__ bias,
                                                short* __restrict__ Qw,
                                                short* __restrict__ Kw,
                                                short* __restrict__ Vw) {
    const int K = DIMC;
    __shared__ float As[16][68];
    __shared__ float Bs[16][68];
    const int m0 = blockIdx.y * 64, n0 = blockIdx.x * 64;
    const int tid = threadIdx.x;
    const int tx = tid & 15, ty = tid >> 4;
    const int lk = tid & 15;
    const int lm = tid >> 4;
    float acc[4][4] = {};

    for (int kt = 0; kt < K; kt += 16) {
#pragma unroll
        for (int i = 0; i < 4; i++) {
            int mm = lm + i * 16;
            As[lk][mm] = X[(size_t)(m0 + mm) * K + kt + lk];
            Bs[lk][mm] = W[(size_t)(n0 + mm) * K + kt + lk];
        }
        __syncthreads();
#pragma unroll
        for (int kk = 0; kk < 16; kk++) {
            float4 a4 = *(const float4*)&As[kk][ty * 4];
            float4 b4 = *(const float4*)&Bs[kk][tx * 4];
            const float av[4] = {a4.x, a4.y, a4.z, a4.w};
            const float bv[4] = {b4.x, b4.y, b4.z, b4.w};
#pragma unroll
            for (int i = 0; i < 4; i++)
#pragma unroll
                for (int j = 0; j < 4; j++) acc[i][j] += av[i] * bv[j];
        }
        __syncthreads();
    }

    const int which = n0 >> 8;  // 0=q 1=k 2=v, block-uniform (64 | 256)
#pragma unroll
    for (int i = 0; i < 4; i++) {
        int t = m0 + ty * 4 + i;
        int bidx = t >> 11;
        int ntok = t & 2047;
#pragma unroll
        for (int j = 0; j < 4; j++) {
            int n = n0 + tx * 4 + j;
            float val = acc[i][j] + bias[n];
            int jj = n & 255;
            int h = jj >> 5, d = jj & 31;
            size_t bh8 = (size_t)(bidx * NHEADS + h);
            if (which == 0)
                Qw[(bh8 * SEQ + ntok) * HDIM + d] = f2bf(val * SCALE);
            else if (which == 1)
                Kw[(bh8 * SEQ + ntok) * HDIM + d] = f2bf(val);
            else
                Vw[(bh8 * HDIM + d) * SEQ + ntok] = f2bf(val);
        }
    }
}

// ---------------------------------------------------------------------------
// MFMA flash attention. grid=(32 qtiles, 32 bh), 256 thr (4 waves).
// Wave w: Q rows q0+w*16..+16. KV tile 64. 8 MFMA / wave / iter.
// C-layout: col=lane&15, row=(lane>>4)*4+reg. A: m=lane&15, k=(lane>>4)*8+j.
// ---------------------------------------------------------------------------
__global__ __launch_bounds__(256) void attn_mfma(const short* __restrict__ Q,
                                                 const short* __restrict__ K,
                                                 const short* __restrict__ V,  // [bh][d][n]
                                                 float* __restrict__ Z) {
    __shared__ __align__(16) short Ks[64][40];   // pad 40: 2-way banks (free)
    __shared__ __align__(16) short Vs[32][72];   // [d][kv], pad 72
    __shared__ __align__(16) float Ps[4][16][68]; // per-wave P, fp32

    const int bh = blockIdx.y;
    const int b = bh >> 3, h = bh & 7;
    const int q0 = blockIdx.x * 64;
    const short* qb = Q + (size_t)bh * SEQ * HDIM;
    const short* kb = K + (size_t)bh * SEQ * HDIM;
    const short* vbase = V + (size_t)bh * HDIM * SEQ;
    const int tid = threadIdx.x;
    const int w = tid >> 6, lane = tid & 63;
    const int m = lane & 15, g = lane >> 4;

    // Q A-frag straight from global (16B/lane, row q0+w*16+m, k=g*8..+8)
    const short8 qfrag = *(const short8*)(qb + (size_t)(q0 + w * 16 + m) * HDIM + g * 8);

    f32x4 o0 = {0.f, 0.f, 0.f, 0.f};
    f32x4 o1 = {0.f, 0.f, 0.f, 0.f};
    float l[4] = {0.f, 0.f, 0.f, 0.f};

    const int kr = tid >> 2, kc = (tid & 3) * 8;   // K stage: 64 rows x 32
    const int vr = tid >> 3, vc = (tid & 7) * 8;   // V stage: 32 rows x 64

    for (int k0 = 0; k0 < SEQ; k0 += 64) {
        short8 kload = *(const short8*)(kb + (size_t)(k0 + kr) * HDIM + kc);
        short8 vload = *(const short8*)(vbase + (size_t)vr * SEQ + k0 + vc);
        __syncthreads();
        *(short8*)&Ks[kr][kc] = kload;
        *(short8*)&Vs[vr][vc] = vload;
        __syncthreads();

        // S = (Q*scale) K^T : 4 MFMAs -> s[t][r] = S[g*4+r][t*16+m]
        f32x4 s[4];
#pragma unroll
        for (int t = 0; t < 4; t++) {
            short8 bfrag = *(const short8*)&Ks[t * 16 + m][g * 8];
            f32x4 zero = {0.f, 0.f, 0.f, 0.f};
            s[t] = __builtin_amdgcn_mfma_f32_16x16x32_bf16(qfrag, bfrag, zero, 0, 0, 0);
        }

        // p = exp(s) (no max subtraction: |s| <= ~1.3), accumulate l, park P
#pragma unroll
        for (int t = 0; t < 4; t++)
#pragma unroll
            for (int r = 0; r < 4; r++) {
                float p = __expf(s[t][r]);
                l[r] += p;
                Ps[w][g * 4 + r][t * 16 + m] = p;
            }

        // O += P V : A-frag from Ps (cvt fp32->bf16), B-frag from Vs
#pragma unroll
        for (int c = 0; c < 2; c++) {
            f32x4 pa = *(const f32x4*)&Ps[w][m][c * 32 + g * 8];
            f32x4 pb = *(const f32x4*)&Ps[w][m][c * 32 + g * 8 + 4];
            short8 af;
            af[0] = f2bf(pa[0]); af[1] = f2bf(pa[1]);
            af[2] = f2bf(pa[2]); af[3] = f2bf(pa[3]);
            af[4] = f2bf(pb[0]); af[5] = f2bf(pb[1]);
            af[6] = f2bf(pb[2]); af[7] = f2bf(pb[3]);
            short8 vb0 = *(const short8*)&Vs[m][c * 32 + g * 8];
            short8 vb1 = *(const short8*)&Vs[m + 16][c * 32 + g * 8];
            o0 = __builtin_amdgcn_mfma_f32_16x16x32_bf16(af, vb0, o0, 0, 0, 0);
            o1 = __builtin_amdgcn_mfma_f32_16x16x32_bf16(af, vb1, o1, 0, 0, 0);
        }
    }

    // deferred l reduction across the 16 lanes sharing each row
#pragma unroll
    for (int r = 0; r < 4; r++) {
#pragma unroll
        for (int off = 1; off < 16; off <<= 1)
            l[r] += __shfl_xor(l[r], off);
    }

    const int row = q0 + w * 16 + g * 4;
#pragma unroll
    for (int r = 0; r < 4; r++) {
        float inv = 1.0f / l[r];
        size_t zo = ((size_t)(b * SEQ + row + r)) * DIMC + h * HDIM + m;
        Z[zo] = o0[r] * inv;
        Z[zo + 16] = o1[r] * inv;
    }
}

// ---------------------------------------------------------------------------
// Out GEMM: fp32, unchanged from round 0.
// ---------------------------------------------------------------------------
__global__ __launch_bounds__(256) void out_gemm(const float* __restrict__ A,
                                                const float* __restrict__ W,
                                                const float* __restrict__ bias,
                                                float* __restrict__ C) {
    const int K = DIMC;
    __shared__ float As[16][68];
    __shared__ float Bs[16][68];
    const int m0 = blockIdx.y * 64, n0 = blockIdx.x * 64;
    const int tid = threadIdx.x;
    const int tx = tid & 15, ty = tid >> 4;
    const int lk = tid & 15;
    const int lm = tid >> 4;
    float acc[4][4] = {};

    for (int kt = 0; kt < K; kt += 16) {
#pragma unroll
        for (int i = 0; i < 4; i++) {
            int mm = lm + i * 16;
            As[lk][mm] = A[(size_t)(m0 + mm) * K + kt + lk];
            Bs[lk][mm] = W[(size_t)(n0 + mm) * K + kt + lk];
        }
        __syncthreads();
#pragma unroll
        for (int kk = 0; kk < 16; kk++) {
            float4 a4 = *(const float4*)&As[kk][ty * 4];
            float4 b4 = *(const float4*)&Bs[kk][tx * 4];
            const float av[4] = {a4.x, a4.y, a4.z, a4.w};
            const float bv[4] = {b4.x, b4.y, b4.z, b4.w};
#pragma unroll
            for (int i = 0; i < 4; i++)
#pragma unroll
                for (int j = 0; j < 4; j++) acc[i][j] += av[i] * bv[j];
        }
        __syncthreads();
    }

#pragma unroll
    for (int i = 0; i < 4; i++) {
        int t = m0 + ty * 4 + i;
#pragma unroll
        for (int j = 0; j < 4; j++) {
            int n = n0 + tx * 4 + j;
            C[(size_t)t * DIMC + n] = acc[i][j] + bias[n];
        }
    }
}

extern "C" void kernel_launch(void* const* d_in, const int* in_sizes, int n_in,
                              void* d_out, int out_size, void* d_ws, size_t ws_size,
                              hipStream_t stream) {
    const float* x     = (const float*)d_in[0];
    const float* w_qkv = (const float*)d_in[1];
    const float* b_qkv = (const float*)d_in[2];
    const float* w_out = (const float*)d_in[3];
    const float* b_out = (const float*)d_in[4];
    float* out = (float*)d_out;

    const size_t HSZ = (size_t)BATCH * NHEADS * SEQ * HDIM;  // 2M elems
    short* qw = (short*)d_ws;
    short* kw = qw + HSZ;
    short* vw = kw + HSZ;
    float* z  = (float*)((char*)d_ws + 3 * HSZ * sizeof(short));  // 12 MB offset

    qkv_gemm<<<dim3(12, 128), 256, 0, stream>>>(x, w_qkv, b_qkv, qw, kw, vw);
    attn_mfma<<<dim3(32, 32), 256, 0, stream>>>(qw, kw, vw, z);
    out_gemm<<<dim3(4, 128), 256, 0, stream>>>(z, w_out, b_out, out);
}

// Round 3
// 131.843 us; speedup vs baseline: 5.4085x; 1.4734x over previous
//
#include <hip/hip_runtime.h>

// Round 2: all three stages on MFMA.
// qkv_mfma: bf16 MFMA GEMM (fp32->bf16 staged), LDS-staged coalesced epilogue
//   -> Q (pre-scaled by SCALE*log2e) / K as [bh][tok][d] bf16, V as [bh][d][tok] bf16.
// attn_mfma: exp2-based softmax (no max-sub, |logit| small), l via ones-MFMA,
//   P packed with v_perm; emits bf16 Z [tok][256].
// out_mfma: bf16 MFMA GEMM -> fp32 out.
// ws: Q 4MB | K 4MB | V 4MB | Zb 4MB = 16 MB.

#define SEQ 2048
#define BATCH 4
#define NHEADS 8
#define HDIM 32
#define DIMC 256
#define SCALE_LOG2E 0.09016844005556021f  // (1/16)*log2(e); exp2((q.k)*this) == softmax exp

typedef __attribute__((ext_vector_type(8))) short short8;
typedef __attribute__((ext_vector_type(4))) float f32x4;

union BF8 { unsigned u[4]; short8 s8; };

// pack two fp32 -> two bf16 (round-half-up) in one dword: [lo]=a, [hi]=b
__device__ __forceinline__ unsigned pk2bf(float a, float b) {
    union { float f; unsigned u; } ua, ub;
    ua.f = a; ub.f = b;
    return __builtin_amdgcn_perm(ub.u + 0x8000u, ua.u + 0x8000u, 0x07060302u);
}
__device__ __forceinline__ short f2bf(float a) {
    union { float f; unsigned u; } x; x.f = a;
    return (short)((x.u + 0x8000u) >> 16);
}

// ---------------------------------------------------------------------------
// QKV GEMM, bf16 MFMA. C[8192][768] = X[8192][256] . W[768][256]^T + b.
// 64x64 tile, 4 waves (wave w = rows w*16..+16), BK=32, 8 K-iters.
// Epilogue: LDS-staged coalesced bf16 scatter per destination layout.
// ---------------------------------------------------------------------------
__global__ __launch_bounds__(256) void qkv_mfma(const float* __restrict__ X,
                                                const float* __restrict__ W,
                                                const float* __restrict__ bias,
                                                short* __restrict__ Q,
                                                short* __restrict__ Kd,
                                                short* __restrict__ V) {
    __shared__ __align__(16) short Xs[64][40];
    __shared__ __align__(16) short Ws[64][40];
    __shared__ __align__(16) short Cs[64][72];
    const int m0 = blockIdx.y * 64, n0 = blockIdx.x * 64;
    const int tid = threadIdx.x;
    const int w = tid >> 6, lane = tid & 63;
    const int m = lane & 15, g = lane >> 4;
    const int srow = tid >> 2, scol = (tid & 3) * 8;

    f32x4 acc[4] = {};

    for (int kt = 0; kt < DIMC; kt += 32) {
        const float* xp = &X[(size_t)(m0 + srow) * DIMC + kt + scol];
        const float* wp = &W[(size_t)(n0 + srow) * DIMC + kt + scol];
        float4 x0 = *(const float4*)xp, x1 = *(const float4*)(xp + 4);
        float4 w0 = *(const float4*)wp, w1 = *(const float4*)(wp + 4);
        __syncthreads();
        BF8 cx, cw;
        cx.u[0] = pk2bf(x0.x, x0.y); cx.u[1] = pk2bf(x0.z, x0.w);
        cx.u[2] = pk2bf(x1.x, x1.y); cx.u[3] = pk2bf(x1.z, x1.w);
        cw.u[0] = pk2bf(w0.x, w0.y); cw.u[1] = pk2bf(w0.z, w0.w);
        cw.u[2] = pk2bf(w1.x, w1.y); cw.u[3] = pk2bf(w1.z, w1.w);
        *(short8*)&Xs[srow][scol] = cx.s8;
        *(short8*)&Ws[srow][scol] = cw.s8;
        __syncthreads();
        short8 afrag = *(const short8*)&Xs[w * 16 + m][g * 8];
#pragma unroll
        for (int t = 0; t < 4; t++) {
            short8 bfrag = *(const short8*)&Ws[t * 16 + m][g * 8];
            acc[t] = __builtin_amdgcn_mfma_f32_16x16x32_bf16(afrag, bfrag, acc[t], 0, 0, 0);
        }
    }

    float bv[4];
#pragma unroll
    for (int t = 0; t < 4; t++) bv[t] = bias[n0 + t * 16 + m];

    const int which = n0 >> 8;           // 0=Q 1=K 2=V (block-uniform)
    const int bidx = m0 >> 11, ntok0 = m0 & 2047;
    const int h0 = (n0 & 255) >> 5;      // first of the 2 heads in this n-tile

    __syncthreads();
    if (which != 2) {
        const float qs = (which == 0) ? SCALE_LOG2E : 1.0f;
#pragma unroll
        for (int t = 0; t < 4; t++)
#pragma unroll
            for (int r = 0; r < 4; r++)
                Cs[w * 16 + g * 4 + r][t * 16 + m] = f2bf((acc[t][r] + bv[t]) * qs);
        __syncthreads();
        short* dst = (which == 0) ? Q : Kd;
#pragma unroll
        for (int hh = 0; hh < 2; hh++) {
            int tok = tid >> 2, d = (tid & 3) * 8;
            short8 val = *(const short8*)&Cs[tok][hh * 32 + d];
            size_t off = ((size_t)((bidx * NHEADS + h0 + hh) * SEQ) + ntok0 + tok) * HDIM + d;
            *(short8*)&dst[off] = val;
        }
    } else {
        // transposed staging for V [bh][d][tok]
#pragma unroll
        for (int t = 0; t < 4; t++)
#pragma unroll
            for (int r = 0; r < 4; r++)
                Cs[t * 16 + m][w * 16 + g * 4 + r] = f2bf(acc[t][r] + bv[t]);
        __syncthreads();
#pragma unroll
        for (int half = 0; half < 2; half++) {
            int c = (tid >> 3) + half * 32, tok = (tid & 7) * 8;
            short8 val = *(const short8*)&Cs[c][tok];
            int hh = c >> 5, d = c & 31;
            size_t off = ((size_t)((bidx * NHEADS + h0 + hh) * HDIM) + d) * SEQ + ntok0 + tok;
            *(short8*)&V[off] = val;
        }
    }
}

// ---------------------------------------------------------------------------
// MFMA flash attention. grid=(32 qtiles, 32 bh), 4 waves; wave = 16 q-rows.
// exp2 softmax (Q pre-scaled by SCALE*log2e); l via ones-MFMA; bf16 Z out.
// ---------------------------------------------------------------------------
__global__ __launch_bounds__(256) void attn_mfma(const short* __restrict__ Q,
                                                 const short* __restrict__ K,
                                                 const short* __restrict__ V,  // [bh][d][n]
                                                 short* __restrict__ Zb) {
    __shared__ __align__(16) short Ks[64][40];
    __shared__ __align__(16) short Vs[32][72];
    __shared__ __align__(16) float Ps[4][16][68];

    const int bh = blockIdx.y;
    const int b = bh >> 3, h = bh & 7;
    const int q0 = blockIdx.x * 64;
    const short* qb = Q + (size_t)bh * SEQ * HDIM;
    const short* kb = K + (size_t)bh * SEQ * HDIM;
    const short* vbase = V + (size_t)bh * HDIM * SEQ;
    const int tid = threadIdx.x;
    const int w = tid >> 6, lane = tid & 63;
    const int m = lane & 15, g = lane >> 4;

    const short8 qfrag = *(const short8*)(qb + (size_t)(q0 + w * 16 + m) * HDIM + g * 8);
    const short8 ones = {0x3F80, 0x3F80, 0x3F80, 0x3F80, 0x3F80, 0x3F80, 0x3F80, 0x3F80};

    f32x4 o0 = {0.f, 0.f, 0.f, 0.f};
    f32x4 o1 = {0.f, 0.f, 0.f, 0.f};
    f32x4 ol = {0.f, 0.f, 0.f, 0.f};

    const int kr = tid >> 2, kc = (tid & 3) * 8;
    const int vr = tid >> 3, vc = (tid & 7) * 8;

    for (int k0 = 0; k0 < SEQ; k0 += 64) {
        short8 kload = *(const short8*)(kb + (size_t)(k0 + kr) * HDIM + kc);
        short8 vload = *(const short8*)(vbase + (size_t)vr * SEQ + k0 + vc);
        __syncthreads();
        *(short8*)&Ks[kr][kc] = kload;
        *(short8*)&Vs[vr][vc] = vload;
        __syncthreads();

        // S = (Q*scale*log2e) K^T
        f32x4 s[4];
#pragma unroll
        for (int t = 0; t < 4; t++) {
            short8 bfrag = *(const short8*)&Ks[t * 16 + m][g * 8];
            f32x4 zero = {0.f, 0.f, 0.f, 0.f};
            s[t] = __builtin_amdgcn_mfma_f32_16x16x32_bf16(qfrag, bfrag, zero, 0, 0, 0);
        }

        // P = exp2(S); park in per-wave LDS (C-layout -> A-layout transform)
#pragma unroll
        for (int t = 0; t < 4; t++)
#pragma unroll
            for (int r = 0; r < 4; r++)
                Ps[w][g * 4 + r][t * 16 + m] = __builtin_amdgcn_exp2f(s[t][r]);

        // O += P V ; l += P.1 (ones-MFMA broadcasts row sums to all lanes)
#pragma unroll
        for (int c = 0; c < 2; c++) {
            f32x4 pa = *(const f32x4*)&Ps[w][m][c * 32 + g * 8];
            f32x4 pb = *(const f32x4*)&Ps[w][m][c * 32 + g * 8 + 4];
            BF8 cv;
            cv.u[0] = pk2bf(pa[0], pa[1]); cv.u[1] = pk2bf(pa[2], pa[3]);
            cv.u[2] = pk2bf(pb[0], pb[1]); cv.u[3] = pk2bf(pb[2], pb[3]);
            short8 vb0 = *(const short8*)&Vs[m][c * 32 + g * 8];
            short8 vb1 = *(const short8*)&Vs[m + 16][c * 32 + g * 8];
            o0 = __builtin_amdgcn_mfma_f32_16x16x32_bf16(cv.s8, vb0, o0, 0, 0, 0);
            o1 = __builtin_amdgcn_mfma_f32_16x16x32_bf16(cv.s8, vb1, o1, 0, 0, 0);
            ol = __builtin_amdgcn_mfma_f32_16x16x32_bf16(cv.s8, ones, ol, 0, 0, 0);
        }
    }

    const int row = q0 + w * 16 + g * 4;
#pragma unroll
    for (int r = 0; r < 4; r++) {
        float inv = __builtin_amdgcn_rcpf(ol[r]);
        size_t zo = ((size_t)(b * SEQ + row + r)) * DIMC + h * HDIM + m;
        Zb[zo] = f2bf(o0[r] * inv);
        Zb[zo + 16] = f2bf(o1[r] * inv);
    }
}

// ---------------------------------------------------------------------------
// Out GEMM, bf16 MFMA. out[8192][256] = Zb[8192][256] . Wout[256][256]^T + b.
// ---------------------------------------------------------------------------
__global__ __launch_bounds__(256) void out_mfma(const short* __restrict__ Zb,
                                                const float* __restrict__ W,
                                                const float* __restrict__ bias,
                                                float* __restrict__ C) {
    __shared__ __align__(16) short As_[64][40];
    __shared__ __align__(16) short Ws[64][40];
    const int m0 = blockIdx.y * 64, n0 = blockIdx.x * 64;
    const int tid = threadIdx.x;
    const int w = tid >> 6, lane = tid & 63;
    const int m = lane & 15, g = lane >> 4;
    const int srow = tid >> 2, scol = (tid & 3) * 8;

    f32x4 acc[4] = {};

    for (int kt = 0; kt < DIMC; kt += 32) {
        short8 a8 = *(const short8*)&Zb[(size_t)(m0 + srow) * DIMC + kt + scol];
        const float* wp = &W[(size_t)(n0 + srow) * DIMC + kt + scol];
        float4 w0 = *(const float4*)wp, w1 = *(const float4*)(wp + 4);
        __syncthreads();
        BF8 cw;
        cw.u[0] = pk2bf(w0.x, w0.y); cw.u[1] = pk2bf(w0.z, w0.w);
        cw.u[2] = pk2bf(w1.x, w1.y); cw.u[3] = pk2bf(w1.z, w1.w);
        *(short8*)&As_[srow][scol] = a8;
        *(short8*)&Ws[srow][scol] = cw.s8;
        __syncthreads();
        short8 afrag = *(const short8*)&As_[w * 16 + m][g * 8];
#pragma unroll
        for (int t = 0; t < 4; t++) {
            short8 bfrag = *(const short8*)&Ws[t * 16 + m][g * 8];
            acc[t] = __builtin_amdgcn_mfma_f32_16x16x32_bf16(afrag, bfrag, acc[t], 0, 0, 0);
        }
    }

    float bv[4];
#pragma unroll
    for (int t = 0; t < 4; t++) bv[t] = bias[n0 + t * 16 + m];
#pragma unroll
    for (int t = 0; t < 4; t++)
#pragma unroll
        for (int r = 0; r < 4; r++)
            C[(size_t)(m0 + w * 16 + g * 4 + r) * DIMC + n0 + t * 16 + m] = acc[t][r] + bv[t];
}

extern "C" void kernel_launch(void* const* d_in, const int* in_sizes, int n_in,
                              void* d_out, int out_size, void* d_ws, size_t ws_size,
                              hipStream_t stream) {
    const float* x     = (const float*)d_in[0];
    const float* w_qkv = (const float*)d_in[1];
    const float* b_qkv = (const float*)d_in[2];
    const float* w_out = (const float*)d_in[3];
    const float* b_out = (const float*)d_in[4];
    float* out = (float*)d_out;

    const size_t HSZ = (size_t)BATCH * NHEADS * SEQ * HDIM;  // 2M elems
    short* qw = (short*)d_ws;
    short* kw = qw + HSZ;
    short* vw = kw + HSZ;
    short* zb = vw + HSZ;

    qkv_mfma<<<dim3(12, 128), 256, 0, stream>>>(x, w_qkv, b_qkv, qw, kw, vw);
    attn_mfma<<<dim3(32, 32), 256, 0, stream>>>(qw, kw, vw, zb);
    out_mfma<<<dim3(4, 128), 256, 0, stream>>>(zb, w_out, b_out, out);
}